// Round 10
// baseline (547.473 us; speedup 1.0000x reference)
//
#include <hip/hip_runtime.h>

#define N_NODES 50000
#define DIM 64
#define EDGE_DIM 32
#define HEADS 8
#define EXP_HEADS 16
#define NEDGE 800000
#define SCALE 0.35355339059327373f  /* 8^-0.5 */
#define EPS 1e-16f
#define NEG_BIG -1e30f

#define RFL(x) __builtin_amdgcn_readfirstlane(x)

// ---- Kernel A: q,k,v = x @ {Wq,Wk,Wv}, 4 nodes per thread ------------------
__global__ __launch_bounds__(256) void qkv_kernel(
    const float* __restrict__ x, const float* __restrict__ Wq,
    const float* __restrict__ Wk, const float* __restrict__ Wv,
    float* __restrict__ q, float* __restrict__ k, float* __restrict__ v) {
    int gid = blockIdx.x * 256 + threadIdx.x;
    if (gid >= (N_NODES / 4) * DIM) return;
    int quad = gid >> 6, j = gid & 63;
    long i0 = (long)quad * 4;
    float aq[4] = {0,0,0,0}, ak[4] = {0,0,0,0}, av[4] = {0,0,0,0};
#pragma unroll
    for (int l = 0; l < DIM; ++l) {
        float wq = Wq[l * DIM + j], wk = Wk[l * DIM + j], wv = Wv[l * DIM + j];
#pragma unroll
        for (int r = 0; r < 4; ++r) {
            float xv = x[(i0 + r) * DIM + l];
            aq[r] = fmaf(xv, wq, aq[r]);
            ak[r] = fmaf(xv, wk, ak[r]);
            av[r] = fmaf(xv, wv, av[r]);
        }
    }
#pragma unroll
    for (int r = 0; r < 4; ++r) {
        q[(i0 + r) * DIM + j] = aq[r];
        k[(i0 + r) * DIM + j] = ak[r];
        v[(i0 + r) * DIM + j] = av[r];
    }
}

// ---- CSR build: histogram --------------------------------------------------
__global__ __launch_bounds__(256) void hist_kernel(
    const int* __restrict__ eidx, unsigned* __restrict__ cnt) {
    int e = blockIdx.x * 256 + threadIdx.x;
    if (e >= NEDGE) return;
    atomicAdd(&cnt[eidx[e]], 1u);
}

// ---- CSR build: single-block exclusive scan over 50k counts ---------------
#define SCAN_T 1024
#define CHUNK 49
__global__ __launch_bounds__(SCAN_T) void scan_kernel(
    const unsigned* __restrict__ cnt, unsigned* __restrict__ offsets,
    unsigned* __restrict__ cursor) {
    __shared__ unsigned ps[SCAN_T];
    int t = threadIdx.x;
    int lo = t * CHUNK, hi = min(lo + CHUNK, N_NODES);
    unsigned loc = 0;
    for (int i = lo; i < hi; ++i) loc += cnt[i];
    ps[t] = loc;
    __syncthreads();
    for (int off = 1; off < SCAN_T; off <<= 1) {
        unsigned val = (t >= off) ? ps[t - off] : 0u;
        __syncthreads();
        ps[t] += val;
        __syncthreads();
    }
    unsigned run = ps[t] - loc;
    for (int i = lo; i < hi; ++i) {
        unsigned c = cnt[i];
        offsets[i] = run; cursor[i] = run; run += c;
    }
    if (t == SCAN_T - 1) offsets[N_NODES] = ps[SCAN_T - 1];
}

// ---- CSR build: scatter edge/dst/src ids into sorted order -----------------
__global__ __launch_bounds__(256) void scatter_kernel(
    const int* __restrict__ eidx, unsigned* __restrict__ cursor,
    unsigned* __restrict__ perm, unsigned* __restrict__ iperm,
    unsigned* __restrict__ srcs, unsigned* __restrict__ dsts) {
    int e = blockIdx.x * 256 + threadIdx.x;
    if (e >= NEDGE) return;
    int dst = eidx[e];
    unsigned pos = atomicAdd(&cursor[dst], 1u);
    perm[pos] = e;
    iperm[e] = pos;
    srcs[pos] = (unsigned)eidx[NEDGE + e];
    dsts[pos] = (unsigned)dst;
}

// ---- L3 warm: stream edges sequentially so random re-reads hit L3 ----------
#define WARM_BLOCKS 2048
__global__ __launch_bounds__(256) void warm_kernel(
    const float4* __restrict__ src, float* __restrict__ dummy) {
    const long n4 = (long)NEDGE * EDGE_DIM / 4;
    long i = (long)blockIdx.x * 256 + threadIdx.x;
    const long stride = (long)WARM_BLOCKS * 256;
    float acc = 0.f;
    for (; i < n4; i += stride) {
        float4 t = src[i];
        acc += t.x + t.y + t.z + t.w;
    }
    // anti-DCE write into logit8 region (fully overwritten by edge_attn)
    dummy[(long)blockIdx.x * 256 + threadIdx.x] = acc;
}

// ---- Kernel B: head logits, NODE-parallel, per-node G in registers ---------
// logit8[slot][h] = (q[n,h]·k[src,h] + edges[e]·G[n,h,:]) * SCALE/temp
// G[n,h,l] = sum_t q[n,h*8+t]*Wek[l][h*8+t], built once per node (branch-free)
__global__ __launch_bounds__(256) void edge_attn_kernel(
    const float* __restrict__ edges,
    const float* __restrict__ q, const float* __restrict__ k,
    const float* __restrict__ Wek,
    const float* __restrict__ temp, const unsigned* __restrict__ perm,
    const unsigned* __restrict__ offsets, const unsigned* __restrict__ srcs,
    float* __restrict__ logit8) {
    int tid = threadIdx.x;
    int w = tid >> 6, lane = tid & 63;
    int h = lane >> 3, d = lane & 7;
    // Wek sub-block for this lane: wekr[j][i] = Wek[d*4+j][h*8+i]
    float wekr[4][8];
#pragma unroll
    for (int j = 0; j < 4; ++j)
#pragma unroll
        for (int i = 0; i < 8; ++i)
            wekr[j][i] = Wek[(d * 4 + j) * DIM + h * 8 + i];
    float invt = SCALE / temp[0];
    int n = blockIdx.x * 4 + w;    // N_NODES % 4 == 0, grid exact
    unsigned nb = offsets[n];
    int deg = (int)(offsets[n + 1] - nb);
    const float* __restrict__ qp = q + (long)n * DIM;
    float qreg = qp[lane];
    float qv[8];
#pragma unroll
    for (int t = 0; t < 8; ++t) qv[t] = qp[h * 8 + t];
    float g0 = 0.f, g1 = 0.f, g2 = 0.f, g3 = 0.f;
#pragma unroll
    for (int t = 0; t < 8; ++t) {
        g0 = fmaf(qv[t], wekr[0][t], g0);
        g1 = fmaf(qv[t], wekr[1][t], g1);
        g2 = fmaf(qv[t], wekr[2][t], g2);
        g3 = fmaf(qv[t], wekr[3][t], g3);
    }
    int j = 0;
    for (; j + 4 <= deg; j += 4) {
        float p[4];
#pragma unroll
        for (int g2i = 0; g2i < 4; ++g2i) {
            long slot = (long)nb + j + g2i;
            int e_g = RFL((int)perm[slot]);
            int s_g = RFL((int)srcs[slot]);
            float kv = k[(long)s_g * DIM + lane];
            float4 ed = *(const float4*)(edges + (long)e_g * EDGE_DIM + d * 4);
            float pp = qreg * kv;
            pp = fmaf(g0, ed.x, pp);
            pp = fmaf(g1, ed.y, pp);
            pp = fmaf(g2, ed.z, pp);
            pp = fmaf(g3, ed.w, pp);
            p[g2i] = pp;
        }
#pragma unroll
        for (int i = 0; i < 4; ++i) p[i] += __shfl_xor(p[i], 1);
#pragma unroll
        for (int i = 0; i < 4; ++i) p[i] += __shfl_xor(p[i], 2);
#pragma unroll
        for (int i = 0; i < 4; ++i) p[i] += __shfl_xor(p[i], 4);
        if (d == 0) {
#pragma unroll
            for (int i = 0; i < 4; ++i)
                logit8[((long)nb + j + i) * HEADS + h] = p[i] * invt;
        }
    }
    for (; j < deg; ++j) {
        long slot = (long)nb + j;
        int e_g = RFL((int)perm[slot]);
        int s_g = RFL((int)srcs[slot]);
        float kv = k[(long)s_g * DIM + lane];
        float4 ed = *(const float4*)(edges + (long)e_g * EDGE_DIM + d * 4);
        float pp = qreg * kv;
        pp = fmaf(g0, ed.x, pp);
        pp = fmaf(g1, ed.y, pp);
        pp = fmaf(g2, ed.z, pp);
        pp = fmaf(g3, ed.w, pp);
        pp += __shfl_xor(pp, 1);
        pp += __shfl_xor(pp, 2);
        pp += __shfl_xor(pp, 4);
        if (d == 0) logit8[slot * HEADS + h] = pp * invt;
    }
}

// ---- Kernel C1: softmax stats, thread per (node, expanded head) ------------
// a(slot,eh) = sum_h logit8[slot][h] * Wexp[h][eh]  (same fma order as a8_kernel)
__global__ __launch_bounds__(256) void stats_kernel(
    const float* __restrict__ logit8, const unsigned* __restrict__ offsets,
    const float* __restrict__ Wexp, float2* __restrict__ stats) {
    int gid = blockIdx.x * 256 + threadIdx.x;   // N*16 = 800k threads
    if (gid >= N_NODES * EXP_HEADS) return;
    int n = gid >> 4, eh = gid & 15;
    float we[HEADS];
#pragma unroll
    for (int hh = 0; hh < HEADS; ++hh) we[hh] = Wexp[hh * EXP_HEADS + eh];
    unsigned nb = offsets[n];
    int deg = (int)(offsets[n + 1] - nb);
    float m = NEG_BIG, s = 0.f;
    for (int j = 0; j < deg; ++j) {
        const float4* lp = (const float4*)(logit8 + (long)(nb + j) * HEADS);
        float4 l0 = lp[0], l1 = lp[1];
        float a = l0.x * we[0];
        a = fmaf(l0.y, we[1], a); a = fmaf(l0.z, we[2], a); a = fmaf(l0.w, we[3], a);
        a = fmaf(l1.x, we[4], a); a = fmaf(l1.y, we[5], a);
        a = fmaf(l1.z, we[6], a); a = fmaf(l1.w, we[7], a);
        float mn = fmaxf(m, a);
        s = s * __expf(m - mn) + __expf(a - mn);
        m = mn;
    }
    float2 st; st.x = m; st.y = 1.f / (s + EPS);
    stats[gid] = st;
}

// ---- Kernel C2: edge-parallel a8 = softmax(attn)@Wsq + bsq -----------------
__global__ __launch_bounds__(256) void a8_kernel(
    const float* __restrict__ logit8, const unsigned* __restrict__ dsts,
    const float2* __restrict__ stats, const float* __restrict__ Wexp,
    const float* __restrict__ Wsq,
    const float* __restrict__ bsq, float* __restrict__ a8s) {
    int tid = threadIdx.x;
    int w = tid >> 6, lane = tid & 63;
    int g = lane >> 4, t16 = lane & 15;
    long slot0 = ((long)blockIdx.x * 4 + w) * 4;   // 4 slots per wave
    float we[HEADS];
#pragma unroll
    for (int hh = 0; hh < HEADS; ++hh) we[hh] = Wexp[hh * EXP_HEADS + t16];
    float wsq[HEADS];
#pragma unroll
    for (int j = 0; j < HEADS; ++j) wsq[j] = Wsq[t16 * HEADS + j];
    int hmap = 4 * (t16 & 1) + 2 * ((t16 >> 1) & 1) + ((t16 >> 2) & 1);
    float bs_w = bsq[hmap];
    bool b0 = (t16 & 1), b1 = (t16 & 2), b2 = (t16 & 4);

    const float4* lp = (const float4*)(logit8 + (slot0 + g) * HEADS);
    float4 l0 = lp[0], l1 = lp[1];          // 16 lanes same row -> L1 broadcast
    float a = l0.x * we[0];
    a = fmaf(l0.y, we[1], a); a = fmaf(l0.z, we[2], a); a = fmaf(l0.w, we[3], a);
    a = fmaf(l1.x, we[4], a); a = fmaf(l1.y, we[5], a);
    a = fmaf(l1.z, we[6], a); a = fmaf(l1.w, we[7], a);
    int dstg = (int)dsts[slot0 + g];
    float2 st = stats[(long)dstg * EXP_HEADS + t16];
    float p = __expf(a - st.x) * st.y;
    float v0 = p * wsq[0], v1 = p * wsq[1], v2 = p * wsq[2], v3 = p * wsq[3];
    float v4 = p * wsq[4], v5 = p * wsq[5], v6 = p * wsq[6], v7 = p * wsq[7];
    float q0, q1, q2, q3, n0, n1, s8;
    q0 = (b0 ? v4 : v0) + __shfl_xor(b0 ? v0 : v4, 1);
    q1 = (b0 ? v5 : v1) + __shfl_xor(b0 ? v1 : v5, 1);
    q2 = (b0 ? v6 : v2) + __shfl_xor(b0 ? v2 : v6, 1);
    q3 = (b0 ? v7 : v3) + __shfl_xor(b0 ? v3 : v7, 1);
    n0 = (b1 ? q2 : q0) + __shfl_xor(b1 ? q0 : q2, 2);
    n1 = (b1 ? q3 : q1) + __shfl_xor(b1 ? q1 : q3, 2);
    s8 = (b2 ? n1 : n0) + __shfl_xor(b2 ? n0 : n1, 4);
    float a8sum = s8 + __shfl_xor(s8, 8);
    if (t16 < 8) a8s[(slot0 + g) * HEADS + hmap] = a8sum + bs_w;
}

// ---- Kernel C3: per-node aggregation (no shfl in loop) ---------------------
__global__ __launch_bounds__(256) void agg_kernel(
    const float* __restrict__ edges, const float* __restrict__ v,
    const float* __restrict__ a8s,
    const unsigned* __restrict__ offsets, const unsigned* __restrict__ perm,
    const unsigned* __restrict__ srcs,
    const float* __restrict__ Wev, float* __restrict__ vmagg) {
    int tid = threadIdx.x;
    int w = tid >> 6, lane = tid & 63;
    int h = lane >> 3, d = lane & 7;
    int n = blockIdx.x * 4 + w;    // N_NODES % 4 == 0, grid exact
    unsigned nb = offsets[n];
    int deg = (int)(offsets[n + 1] - nb);
    float acc = 0.f, t0 = 0.f, t1 = 0.f, t2 = 0.f, t3 = 0.f;
    int j = 0;
    for (; j + 4 <= deg; j += 4) {
#pragma unroll
        for (int g2 = 0; g2 < 4; ++g2) {
            long slot = (long)nb + j + g2;
            int e_g = RFL((int)perm[slot]);
            int s_g = RFL((int)srcs[slot]);
            float a8 = a8s[slot * HEADS + h];
            float vv = v[(long)s_g * DIM + lane];
            float4 ed = *(const float4*)(edges + (long)e_g * EDGE_DIM + d * 4);
            acc = fmaf(a8, vv, acc);
            t0 = fmaf(a8, ed.x, t0);
            t1 = fmaf(a8, ed.y, t1);
            t2 = fmaf(a8, ed.z, t2);
            t3 = fmaf(a8, ed.w, t3);
        }
    }
    for (; j < deg; ++j) {
        long slot = (long)nb + j;
        int e_g = RFL((int)perm[slot]);
        int s_g = RFL((int)srcs[slot]);
        float a8 = a8s[slot * HEADS + h];
        float vv = v[(long)s_g * DIM + lane];
        float4 ed = *(const float4*)(edges + (long)e_g * EDGE_DIM + d * 4);
        acc = fmaf(a8, vv, acc);
        t0 = fmaf(a8, ed.x, t0);
        t1 = fmaf(a8, ed.y, t1);
        t2 = fmaf(a8, ed.z, t2);
        t3 = fmaf(a8, ed.w, t3);
    }
    // ev = t[h][:] @ Wev — t[h][l] on lane h*8+(l>>2), reg t_{l&3}
    float ev = 0.f;
#pragma unroll
    for (int l = 0; l < EDGE_DIM; ++l) {
        float tv = ((l & 3) == 0) ? t0 : ((l & 3) == 1) ? t1 : ((l & 3) == 2) ? t2 : t3;
        float tl = __shfl(tv, h * 8 + (l >> 2));
        ev = fmaf(tl, Wev[l * DIM + lane], ev);
    }
    vmagg[(long)n * DIM + lane] = v[(long)n * DIM + lane] - (acc + ev);
}

// ---- transpose a8s (sorted [E,8]) -> attn.T [8,E] via iperm ---------------
__global__ __launch_bounds__(256) void transpose_kernel(
    const float* __restrict__ a8s, const unsigned* __restrict__ iperm,
    float* __restrict__ out2) {
    int e = blockIdx.x * 256 + threadIdx.x;
    if (e >= NEDGE) return;
    long sj = iperm[e];
    const float4* p = (const float4*)(a8s + sj * HEADS);
    float4 lo = p[0], hi = p[1];
    out2[0L * NEDGE + e] = lo.x; out2[1L * NEDGE + e] = lo.y;
    out2[2L * NEDGE + e] = lo.z; out2[3L * NEDGE + e] = lo.w;
    out2[4L * NEDGE + e] = hi.x; out2[5L * NEDGE + e] = hi.y;
    out2[6L * NEDGE + e] = hi.z; out2[7L * NEDGE + e] = hi.w;
}

// ---- Kernel E: out = vmagg @ Wout + bout, 4 nodes per thread ---------------
__global__ __launch_bounds__(256) void out_kernel(
    const float* __restrict__ vmagg, const float* __restrict__ Wout,
    const float* __restrict__ bout, float* __restrict__ out) {
    int gid = blockIdx.x * 256 + threadIdx.x;
    if (gid >= (N_NODES / 4) * DIM) return;
    int quad = gid >> 6, j = gid & 63;
    long i0 = (long)quad * 4;
    float b = bout[j];
    float ac[4] = {b, b, b, b};
#pragma unroll
    for (int l = 0; l < DIM; ++l) {
        float wv = Wout[l * DIM + j];
#pragma unroll
        for (int r = 0; r < 4; ++r)
            ac[r] = fmaf(vmagg[(i0 + r) * DIM + l], wv, ac[r]);
    }
#pragma unroll
    for (int r = 0; r < 4; ++r) out[(i0 + r) * DIM + j] = ac[r];
}

extern "C" void kernel_launch(void* const* d_in, const int* in_sizes, int n_in,
                              void* d_out, int out_size, void* d_ws, size_t ws_size,
                              hipStream_t stream) {
    const float* x     = (const float*)d_in[0];
    const float* edges = (const float*)d_in[1];
    const int*   eidx  = (const int*)d_in[2];
    const float* Wq    = (const float*)d_in[3];
    const float* Wk    = (const float*)d_in[4];
    const float* Wv    = (const float*)d_in[5];
    const float* Wek   = (const float*)d_in[6];
    const float* Wev   = (const float*)d_in[7];
    const float* Wexp  = (const float*)d_in[8];
    const float* Wsq   = (const float*)d_in[9];
    const float* bsq   = (const float*)d_in[10];
    const float* Wout  = (const float*)d_in[11];
    const float* bout  = (const float*)d_in[12];
    const float* temp  = (const float*)d_in[13];

    float* ws = (float*)d_ws;
    float* q       = ws;                                  // 3.2M floats
    float* k       = q + (long)N_NODES * DIM;             // 3.2M
    float* v       = k + (long)N_NODES * DIM;             // 3.2M
    float* logit8  = v + (long)N_NODES * DIM;             // 6.4M used ([E,8]); region 12.8M
    float* vmagg   = logit8 + (long)NEDGE * EXP_HEADS;    // 3.2M region
    float* a8s     = q;  // aliases q+k (dead after edge_attn); 6.4M
    // stats + dsts alias the vmagg region (dead before agg_kernel writes it)
    float2*   stats  = (float2*)vmagg;                          // 800k float2
    unsigned* dsts   = (unsigned*)(vmagg + 1600000L);           // 800k u32
    unsigned* perm    = (unsigned*)(vmagg + (long)N_NODES * DIM);  // 800k
    unsigned* iperm   = perm + NEDGE;                              // 800k
    unsigned* srcs    = iperm + NEDGE;                             // 800k
    unsigned* cnt     = srcs + NEDGE;                              // 50k
    unsigned* offsets = cnt + N_NODES;                             // 50001
    unsigned* cursor  = offsets + N_NODES + 1;                     // 50k

    hipMemsetAsync(cnt, 0, (size_t)N_NODES * sizeof(unsigned), stream);

    float* out1 = (float*)d_out;               // [N, 64]
    float* out2 = out1 + (long)N_NODES * DIM;  // [8, E]

    qkv_kernel<<<(N_NODES / 4 * DIM + 255) / 256, 256, 0, stream>>>(x, Wq, Wk, Wv, q, k, v);
    hist_kernel<<<(NEDGE + 255) / 256, 256, 0, stream>>>(eidx, cnt);
    scan_kernel<<<1, SCAN_T, 0, stream>>>(cnt, offsets, cursor);
    warm_kernel<<<WARM_BLOCKS, 256, 0, stream>>>((const float4*)edges, logit8);
    scatter_kernel<<<(NEDGE + 255) / 256, 256, 0, stream>>>(eidx, cursor, perm, iperm, srcs, dsts);
    edge_attn_kernel<<<N_NODES / 4, 256, 0, stream>>>(edges, q, k, Wek, temp,
                                                      perm, offsets, srcs, logit8);
    stats_kernel<<<(N_NODES * EXP_HEADS + 255) / 256, 256, 0, stream>>>(logit8, offsets, Wexp, stats);
    a8_kernel<<<NEDGE / 16, 256, 0, stream>>>(logit8, dsts, stats, Wexp, Wsq, bsq, a8s);
    agg_kernel<<<N_NODES / 4, 256, 0, stream>>>(edges, v, a8s, offsets, perm, srcs, Wev, vmagg);
    transpose_kernel<<<(NEDGE + 255) / 256, 256, 0, stream>>>(a8s, iperm, out2);
    out_kernel<<<(N_NODES / 4 * DIM + 255) / 256, 256, 0, stream>>>(vmagg, Wout, bout, out1);
}

// Round 11
// 450.698 us; speedup vs baseline: 1.2147x; 1.2147x over previous
//
#include <hip/hip_runtime.h>

#define N_NODES 50000
#define DIM 64
#define EDGE_DIM 32
#define HEADS 8
#define EXP_HEADS 16
#define NEDGE 800000
#define SCALE 0.35355339059327373f  /* 8^-0.5 */
#define EPS 1e-16f
#define NEG_BIG -1e30f
#define NB_SCAN ((N_NODES + 255) / 256)   /* 196 */

#define RFL(x) __builtin_amdgcn_readfirstlane(x)

// ---- Kernel A: q,k,v = x @ {Wq,Wk,Wv}, 4 nodes per thread ------------------
__global__ __launch_bounds__(256) void qkv_kernel(
    const float* __restrict__ x, const float* __restrict__ Wq,
    const float* __restrict__ Wk, const float* __restrict__ Wv,
    float* __restrict__ q, float* __restrict__ k, float* __restrict__ v) {
    int gid = blockIdx.x * 256 + threadIdx.x;
    if (gid >= (N_NODES / 4) * DIM) return;
    int quad = gid >> 6, j = gid & 63;
    long i0 = (long)quad * 4;
    float aq[4] = {0,0,0,0}, ak[4] = {0,0,0,0}, av[4] = {0,0,0,0};
#pragma unroll
    for (int l = 0; l < DIM; ++l) {
        float wq = Wq[l * DIM + j], wk = Wk[l * DIM + j], wv = Wv[l * DIM + j];
#pragma unroll
        for (int r = 0; r < 4; ++r) {
            float xv = x[(i0 + r) * DIM + l];
            aq[r] = fmaf(xv, wq, aq[r]);
            ak[r] = fmaf(xv, wk, ak[r]);
            av[r] = fmaf(xv, wv, av[r]);
        }
    }
#pragma unroll
    for (int r = 0; r < 4; ++r) {
        q[(i0 + r) * DIM + j] = aq[r];
        k[(i0 + r) * DIM + j] = ak[r];
        v[(i0 + r) * DIM + j] = av[r];
    }
}

// ---- CSR build: histogram --------------------------------------------------
__global__ __launch_bounds__(256) void hist_kernel(
    const int* __restrict__ eidx, unsigned* __restrict__ cnt) {
    int e = blockIdx.x * 256 + threadIdx.x;
    if (e >= NEDGE) return;
    atomicAdd(&cnt[eidx[e]], 1u);
}

// ---- CSR build: 3-phase multi-block exclusive scan -------------------------
__global__ __launch_bounds__(256) void scan_reduce(
    const unsigned* __restrict__ cnt, unsigned* __restrict__ blocksum) {
    int gid = blockIdx.x * 256 + threadIdx.x;
    unsigned v = (gid < N_NODES) ? cnt[gid] : 0u;
    v += __shfl_xor(v, 1);  v += __shfl_xor(v, 2);
    v += __shfl_xor(v, 4);  v += __shfl_xor(v, 8);
    v += __shfl_xor(v, 16); v += __shfl_xor(v, 32);
    __shared__ unsigned ws4[4];
    if ((threadIdx.x & 63) == 0) ws4[threadIdx.x >> 6] = v;
    __syncthreads();
    if (threadIdx.x == 0)
        blocksum[blockIdx.x] = ws4[0] + ws4[1] + ws4[2] + ws4[3];
}

__global__ __launch_bounds__(256) void scan_base(
    const unsigned* __restrict__ blocksum, unsigned* __restrict__ blockbase) {
    __shared__ unsigned ps[256];
    int t = threadIdx.x;
    unsigned v = (t < NB_SCAN) ? blocksum[t] : 0u;
    ps[t] = v;
    __syncthreads();
    for (int off = 1; off < 256; off <<= 1) {
        unsigned val = (t >= off) ? ps[t - off] : 0u;
        __syncthreads();
        ps[t] += val;
        __syncthreads();
    }
    blockbase[t] = ps[t] - v;   // exclusive
}

__global__ __launch_bounds__(256) void scan_final(
    const unsigned* __restrict__ cnt, const unsigned* __restrict__ blockbase,
    unsigned* __restrict__ offsets, unsigned* __restrict__ cursor) {
    __shared__ unsigned ps[256];
    int t = threadIdx.x;
    int gid = blockIdx.x * 256 + t;
    unsigned v = (gid < N_NODES) ? cnt[gid] : 0u;
    ps[t] = v;
    __syncthreads();
    for (int off = 1; off < 256; off <<= 1) {
        unsigned val = (t >= off) ? ps[t - off] : 0u;
        __syncthreads();
        ps[t] += val;
        __syncthreads();
    }
    unsigned off_ = blockbase[blockIdx.x] + ps[t] - v;
    if (gid < N_NODES) { offsets[gid] = off_; cursor[gid] = off_; }
    if (gid == N_NODES - 1) offsets[N_NODES] = off_ + v;
}

// ---- CSR build: scatter edge/dst/src ids into sorted order -----------------
__global__ __launch_bounds__(256) void scatter_kernel(
    const int* __restrict__ eidx, unsigned* __restrict__ cursor,
    unsigned* __restrict__ perm, unsigned* __restrict__ iperm,
    unsigned* __restrict__ srcs, unsigned* __restrict__ dsts) {
    int e = blockIdx.x * 256 + threadIdx.x;
    if (e >= NEDGE) return;
    int dst = eidx[e];
    unsigned pos = atomicAdd(&cursor[dst], 1u);
    perm[pos] = e;
    iperm[e] = pos;
    srcs[pos] = (unsigned)eidx[NEDGE + e];
    dsts[pos] = (unsigned)dst;
}

// ---- L3 warm: stream edges sequentially so random re-reads hit L3 ----------
#define WARM_BLOCKS 2048
__global__ __launch_bounds__(256) void warm_kernel(
    const float4* __restrict__ src, float* __restrict__ dummy) {
    const long n4 = (long)NEDGE * EDGE_DIM / 4;
    long i = (long)blockIdx.x * 256 + threadIdx.x;
    const long stride = (long)WARM_BLOCKS * 256;
    float acc = 0.f;
    for (; i < n4; i += stride) {
        float4 t = src[i];
        acc += t.x + t.y + t.z + t.w;
    }
    // anti-DCE write into logit8 region (fully overwritten by edge_attn)
    dummy[(long)blockIdx.x * 256 + threadIdx.x] = acc;
}

// ---- Kernel B: head logits, NODE-parallel, per-node G in registers ---------
// logit8[slot][h] = (q[n,h]·k[src,h] + edges[e]·G[n,h,:]) * SCALE/temp
// G[n,h,l] = sum_t q[n,h*8+t]*Wek[l][h*8+t], built once per node (branch-free)
__global__ __launch_bounds__(256) void edge_attn_kernel(
    const float* __restrict__ edges,
    const float* __restrict__ q, const float* __restrict__ k,
    const float* __restrict__ Wek,
    const float* __restrict__ temp, const unsigned* __restrict__ perm,
    const unsigned* __restrict__ offsets, const unsigned* __restrict__ srcs,
    float* __restrict__ logit8) {
    int tid = threadIdx.x;
    int w = tid >> 6, lane = tid & 63;
    int h = lane >> 3, d = lane & 7;
    // Wek sub-block for this lane: wekr[j][i] = Wek[d*4+j][h*8+i]
    float wekr[4][8];
#pragma unroll
    for (int j = 0; j < 4; ++j)
#pragma unroll
        for (int i = 0; i < 8; ++i)
            wekr[j][i] = Wek[(d * 4 + j) * DIM + h * 8 + i];
    float invt = SCALE / temp[0];
    int n = blockIdx.x * 4 + w;    // N_NODES % 4 == 0, grid exact
    unsigned nb = offsets[n];
    int deg = (int)(offsets[n + 1] - nb);
    const float* __restrict__ qp = q + (long)n * DIM;
    float qreg = qp[lane];
    float qv[8];
#pragma unroll
    for (int t = 0; t < 8; ++t) qv[t] = qp[h * 8 + t];
    float g0 = 0.f, g1 = 0.f, g2 = 0.f, g3 = 0.f;
#pragma unroll
    for (int t = 0; t < 8; ++t) {
        g0 = fmaf(qv[t], wekr[0][t], g0);
        g1 = fmaf(qv[t], wekr[1][t], g1);
        g2 = fmaf(qv[t], wekr[2][t], g2);
        g3 = fmaf(qv[t], wekr[3][t], g3);
    }
    int j = 0;
    for (; j + 4 <= deg; j += 4) {
        float p[4];
#pragma unroll
        for (int g2i = 0; g2i < 4; ++g2i) {
            long slot = (long)nb + j + g2i;
            int e_g = RFL((int)perm[slot]);
            int s_g = RFL((int)srcs[slot]);
            float kv = k[(long)s_g * DIM + lane];
            float4 ed = *(const float4*)(edges + (long)e_g * EDGE_DIM + d * 4);
            float pp = qreg * kv;
            pp = fmaf(g0, ed.x, pp);
            pp = fmaf(g1, ed.y, pp);
            pp = fmaf(g2, ed.z, pp);
            pp = fmaf(g3, ed.w, pp);
            p[g2i] = pp;
        }
#pragma unroll
        for (int i = 0; i < 4; ++i) p[i] += __shfl_xor(p[i], 1);
#pragma unroll
        for (int i = 0; i < 4; ++i) p[i] += __shfl_xor(p[i], 2);
#pragma unroll
        for (int i = 0; i < 4; ++i) p[i] += __shfl_xor(p[i], 4);
        if (d == 0) {
#pragma unroll
            for (int i = 0; i < 4; ++i)
                logit8[((long)nb + j + i) * HEADS + h] = p[i] * invt;
        }
    }
    for (; j < deg; ++j) {
        long slot = (long)nb + j;
        int e_g = RFL((int)perm[slot]);
        int s_g = RFL((int)srcs[slot]);
        float kv = k[(long)s_g * DIM + lane];
        float4 ed = *(const float4*)(edges + (long)e_g * EDGE_DIM + d * 4);
        float pp = qreg * kv;
        pp = fmaf(g0, ed.x, pp);
        pp = fmaf(g1, ed.y, pp);
        pp = fmaf(g2, ed.z, pp);
        pp = fmaf(g3, ed.w, pp);
        pp += __shfl_xor(pp, 1);
        pp += __shfl_xor(pp, 2);
        pp += __shfl_xor(pp, 4);
        if (d == 0) logit8[slot * HEADS + h] = pp * invt;
    }
}

// ---- Kernel C1: softmax stats, thread per (node, expanded head) ------------
// a(slot,eh) = sum_h logit8[slot][h] * Wexp[h][eh]  (same fma order as a8_kernel)
__global__ __launch_bounds__(256) void stats_kernel(
    const float* __restrict__ logit8, const unsigned* __restrict__ offsets,
    const float* __restrict__ Wexp, float2* __restrict__ stats) {
    int gid = blockIdx.x * 256 + threadIdx.x;   // N*16 = 800k threads
    if (gid >= N_NODES * EXP_HEADS) return;
    int n = gid >> 4, eh = gid & 15;
    float we[HEADS];
#pragma unroll
    for (int hh = 0; hh < HEADS; ++hh) we[hh] = Wexp[hh * EXP_HEADS + eh];
    unsigned nb = offsets[n];
    int deg = (int)(offsets[n + 1] - nb);
    float m = NEG_BIG, s = 0.f;
    for (int j = 0; j < deg; ++j) {
        const float4* lp = (const float4*)(logit8 + (long)(nb + j) * HEADS);
        float4 l0 = lp[0], l1 = lp[1];
        float a = l0.x * we[0];
        a = fmaf(l0.y, we[1], a); a = fmaf(l0.z, we[2], a); a = fmaf(l0.w, we[3], a);
        a = fmaf(l1.x, we[4], a); a = fmaf(l1.y, we[5], a);
        a = fmaf(l1.z, we[6], a); a = fmaf(l1.w, we[7], a);
        float mn = fmaxf(m, a);
        s = s * __expf(m - mn) + __expf(a - mn);
        m = mn;
    }
    float2 st; st.x = m; st.y = 1.f / (s + EPS);
    stats[gid] = st;
}

// ---- Kernel C2: edge-parallel a8 = softmax(attn)@Wsq + bsq -----------------
__global__ __launch_bounds__(256) void a8_kernel(
    const float* __restrict__ logit8, const unsigned* __restrict__ dsts,
    const float2* __restrict__ stats, const float* __restrict__ Wexp,
    const float* __restrict__ Wsq,
    const float* __restrict__ bsq, float* __restrict__ a8s) {
    int tid = threadIdx.x;
    int w = tid >> 6, lane = tid & 63;
    int g = lane >> 4, t16 = lane & 15;
    long slot0 = ((long)blockIdx.x * 4 + w) * 4;   // 4 slots per wave
    float we[HEADS];
#pragma unroll
    for (int hh = 0; hh < HEADS; ++hh) we[hh] = Wexp[hh * EXP_HEADS + t16];
    float wsq[HEADS];
#pragma unroll
    for (int j = 0; j < HEADS; ++j) wsq[j] = Wsq[t16 * HEADS + j];
    int hmap = 4 * (t16 & 1) + 2 * ((t16 >> 1) & 1) + ((t16 >> 2) & 1);
    float bs_w = bsq[hmap];
    bool b0 = (t16 & 1), b1 = (t16 & 2), b2 = (t16 & 4);

    const float4* lp = (const float4*)(logit8 + (slot0 + g) * HEADS);
    float4 l0 = lp[0], l1 = lp[1];          // 16 lanes same row -> L1 broadcast
    float a = l0.x * we[0];
    a = fmaf(l0.y, we[1], a); a = fmaf(l0.z, we[2], a); a = fmaf(l0.w, we[3], a);
    a = fmaf(l1.x, we[4], a); a = fmaf(l1.y, we[5], a);
    a = fmaf(l1.z, we[6], a); a = fmaf(l1.w, we[7], a);
    int dstg = (int)dsts[slot0 + g];
    float2 st = stats[(long)dstg * EXP_HEADS + t16];
    float p = __expf(a - st.x) * st.y;
    float v0 = p * wsq[0], v1 = p * wsq[1], v2 = p * wsq[2], v3 = p * wsq[3];
    float v4 = p * wsq[4], v5 = p * wsq[5], v6 = p * wsq[6], v7 = p * wsq[7];
    float q0, q1, q2, q3, n0, n1, s8;
    q0 = (b0 ? v4 : v0) + __shfl_xor(b0 ? v0 : v4, 1);
    q1 = (b0 ? v5 : v1) + __shfl_xor(b0 ? v1 : v5, 1);
    q2 = (b0 ? v6 : v2) + __shfl_xor(b0 ? v2 : v6, 1);
    q3 = (b0 ? v7 : v3) + __shfl_xor(b0 ? v3 : v7, 1);
    n0 = (b1 ? q2 : q0) + __shfl_xor(b1 ? q0 : q2, 2);
    n1 = (b1 ? q3 : q1) + __shfl_xor(b1 ? q1 : q3, 2);
    s8 = (b2 ? n1 : n0) + __shfl_xor(b2 ? n0 : n1, 4);
    float a8sum = s8 + __shfl_xor(s8, 8);
    if (t16 < 8) a8s[(slot0 + g) * HEADS + hmap] = a8sum + bs_w;
}

// ---- Kernel C3: per-node aggregation (no shfl in loop) ---------------------
__global__ __launch_bounds__(256) void agg_kernel(
    const float* __restrict__ edges, const float* __restrict__ v,
    const float* __restrict__ a8s,
    const unsigned* __restrict__ offsets, const unsigned* __restrict__ perm,
    const unsigned* __restrict__ srcs,
    const float* __restrict__ Wev, float* __restrict__ vmagg) {
    int tid = threadIdx.x;
    int w = tid >> 6, lane = tid & 63;
    int h = lane >> 3, d = lane & 7;
    int n = blockIdx.x * 4 + w;    // N_NODES % 4 == 0, grid exact
    unsigned nb = offsets[n];
    int deg = (int)(offsets[n + 1] - nb);
    float acc = 0.f, t0 = 0.f, t1 = 0.f, t2 = 0.f, t3 = 0.f;
    int j = 0;
    for (; j + 4 <= deg; j += 4) {
#pragma unroll
        for (int g2 = 0; g2 < 4; ++g2) {
            long slot = (long)nb + j + g2;
            int e_g = RFL((int)perm[slot]);
            int s_g = RFL((int)srcs[slot]);
            float a8 = a8s[slot * HEADS + h];
            float vv = v[(long)s_g * DIM + lane];
            float4 ed = *(const float4*)(edges + (long)e_g * EDGE_DIM + d * 4);
            acc = fmaf(a8, vv, acc);
            t0 = fmaf(a8, ed.x, t0);
            t1 = fmaf(a8, ed.y, t1);
            t2 = fmaf(a8, ed.z, t2);
            t3 = fmaf(a8, ed.w, t3);
        }
    }
    for (; j < deg; ++j) {
        long slot = (long)nb + j;
        int e_g = RFL((int)perm[slot]);
        int s_g = RFL((int)srcs[slot]);
        float a8 = a8s[slot * HEADS + h];
        float vv = v[(long)s_g * DIM + lane];
        float4 ed = *(const float4*)(edges + (long)e_g * EDGE_DIM + d * 4);
        acc = fmaf(a8, vv, acc);
        t0 = fmaf(a8, ed.x, t0);
        t1 = fmaf(a8, ed.y, t1);
        t2 = fmaf(a8, ed.z, t2);
        t3 = fmaf(a8, ed.w, t3);
    }
    // ev = t[h][:] @ Wev — t[h][l] on lane h*8+(l>>2), reg t_{l&3}
    float ev = 0.f;
#pragma unroll
    for (int l = 0; l < EDGE_DIM; ++l) {
        float tv = ((l & 3) == 0) ? t0 : ((l & 3) == 1) ? t1 : ((l & 3) == 2) ? t2 : t3;
        float tl = __shfl(tv, h * 8 + (l >> 2));
        ev = fmaf(tl, Wev[l * DIM + lane], ev);
    }
    vmagg[(long)n * DIM + lane] = v[(long)n * DIM + lane] - (acc + ev);
}

// ---- transpose a8s (sorted [E,8]) -> attn.T [8,E] via iperm ---------------
__global__ __launch_bounds__(256) void transpose_kernel(
    const float* __restrict__ a8s, const unsigned* __restrict__ iperm,
    float* __restrict__ out2) {
    int e = blockIdx.x * 256 + threadIdx.x;
    if (e >= NEDGE) return;
    long sj = iperm[e];
    const float4* p = (const float4*)(a8s + sj * HEADS);
    float4 lo = p[0], hi = p[1];
    out2[0L * NEDGE + e] = lo.x; out2[1L * NEDGE + e] = lo.y;
    out2[2L * NEDGE + e] = lo.z; out2[3L * NEDGE + e] = lo.w;
    out2[4L * NEDGE + e] = hi.x; out2[5L * NEDGE + e] = hi.y;
    out2[6L * NEDGE + e] = hi.z; out2[7L * NEDGE + e] = hi.w;
}

// ---- Kernel E: out = vmagg @ Wout + bout, 4 nodes per thread ---------------
__global__ __launch_bounds__(256) void out_kernel(
    const float* __restrict__ vmagg, const float* __restrict__ Wout,
    const float* __restrict__ bout, float* __restrict__ out) {
    int gid = blockIdx.x * 256 + threadIdx.x;
    if (gid >= (N_NODES / 4) * DIM) return;
    int quad = gid >> 6, j = gid & 63;
    long i0 = (long)quad * 4;
    float b = bout[j];
    float ac[4] = {b, b, b, b};
#pragma unroll
    for (int l = 0; l < DIM; ++l) {
        float wv = Wout[l * DIM + j];
#pragma unroll
        for (int r = 0; r < 4; ++r)
            ac[r] = fmaf(vmagg[(i0 + r) * DIM + l], wv, ac[r]);
    }
#pragma unroll
    for (int r = 0; r < 4; ++r) out[(i0 + r) * DIM + j] = ac[r];
}

extern "C" void kernel_launch(void* const* d_in, const int* in_sizes, int n_in,
                              void* d_out, int out_size, void* d_ws, size_t ws_size,
                              hipStream_t stream) {
    const float* x     = (const float*)d_in[0];
    const float* edges = (const float*)d_in[1];
    const int*   eidx  = (const int*)d_in[2];
    const float* Wq    = (const float*)d_in[3];
    const float* Wk    = (const float*)d_in[4];
    const float* Wv    = (const float*)d_in[5];
    const float* Wek   = (const float*)d_in[6];
    const float* Wev   = (const float*)d_in[7];
    const float* Wexp  = (const float*)d_in[8];
    const float* Wsq   = (const float*)d_in[9];
    const float* bsq   = (const float*)d_in[10];
    const float* Wout  = (const float*)d_in[11];
    const float* bout  = (const float*)d_in[12];
    const float* temp  = (const float*)d_in[13];

    float* ws = (float*)d_ws;
    float* q       = ws;                                  // 3.2M floats
    float* k       = q + (long)N_NODES * DIM;             // 3.2M
    float* v       = k + (long)N_NODES * DIM;             // 3.2M
    float* logit8  = v + (long)N_NODES * DIM;             // 6.4M used ([E,8]); region 12.8M
    float* vmagg   = logit8 + (long)NEDGE * EXP_HEADS;    // 3.2M region
    float* a8s     = q;  // aliases q+k (dead after edge_attn); 6.4M
    // stats + dsts alias the vmagg region (dead before agg_kernel writes it)
    float2*   stats  = (float2*)vmagg;                          // 800k float2
    unsigned* dsts   = (unsigned*)(vmagg + 1600000L);           // 800k u32
    unsigned* perm    = (unsigned*)(vmagg + (long)N_NODES * DIM);  // 800k
    unsigned* iperm   = perm + NEDGE;                              // 800k
    unsigned* srcs    = iperm + NEDGE;                             // 800k
    unsigned* cnt     = srcs + NEDGE;                              // 50k
    unsigned* offsets = cnt + N_NODES;                             // 50001
    unsigned* cursor  = offsets + N_NODES + 1;                     // 50k
    unsigned* blocksum  = cursor + N_NODES;                        // 196
    unsigned* blockbase = blocksum + 256;                          // 256

    hipMemsetAsync(cnt, 0, (size_t)N_NODES * sizeof(unsigned), stream);

    float* out1 = (float*)d_out;               // [N, 64]
    float* out2 = out1 + (long)N_NODES * DIM;  // [8, E]

    qkv_kernel<<<(N_NODES / 4 * DIM + 255) / 256, 256, 0, stream>>>(x, Wq, Wk, Wv, q, k, v);
    hist_kernel<<<(NEDGE + 255) / 256, 256, 0, stream>>>(eidx, cnt);
    scan_reduce<<<NB_SCAN, 256, 0, stream>>>(cnt, blocksum);
    scan_base<<<1, 256, 0, stream>>>(blocksum, blockbase);
    scan_final<<<NB_SCAN, 256, 0, stream>>>(cnt, blockbase, offsets, cursor);
    warm_kernel<<<WARM_BLOCKS, 256, 0, stream>>>((const float4*)edges, logit8);
    scatter_kernel<<<(NEDGE + 255) / 256, 256, 0, stream>>>(eidx, cursor, perm, iperm, srcs, dsts);
    edge_attn_kernel<<<N_NODES / 4, 256, 0, stream>>>(edges, q, k, Wek, temp,
                                                      perm, offsets, srcs, logit8);
    stats_kernel<<<(N_NODES * EXP_HEADS + 255) / 256, 256, 0, stream>>>(logit8, offsets, Wexp, stats);
    a8_kernel<<<NEDGE / 16, 256, 0, stream>>>(logit8, dsts, stats, Wexp, Wsq, bsq, a8s);
    agg_kernel<<<N_NODES / 4, 256, 0, stream>>>(edges, v, a8s, offsets, perm, srcs, Wev, vmagg);
    transpose_kernel<<<(NEDGE + 255) / 256, 256, 0, stream>>>(a8s, iperm, out2);
    out_kernel<<<(N_NODES / 4 * DIM + 255) / 256, 256, 0, stream>>>(vmagg, Wout, bout, out1);
}